// Round 1
// baseline (503.736 us; speedup 1.0000x reference)
//
#include <hip/hip_runtime.h>
#include <cstdint>
#include <cstddef>

#define N_NODES 8192
#define F_OUT   64
#define DINT    32
#define ALPHA   0.2f

// ---------------------------------------------------------------------------
// K1: h = x @ W  (8192x64 @ 64x64), fused s,t projections.
// One block = one row i = one wave of 64 lanes; lane f owns h[i,f].
// s_i = h[i,:]@a[0:64]   + ie[i,:]@a[128:160]
// t_i = h[i,:]@a[64:128] + ie[i,:]@a[160:192]
// ---------------------------------------------------------------------------
__global__ __launch_bounds__(64) void k_h_st(
    const float* __restrict__ x, const float* __restrict__ ie,
    const float* __restrict__ W, const float* __restrict__ a,
    float* __restrict__ h, float* __restrict__ s, float* __restrict__ t)
{
    const int i = blockIdx.x;
    const int f = threadIdx.x;              // 0..63
    const float* xr = x + (size_t)i * 64;

    float acc = 0.f;
    #pragma unroll 16
    for (int k = 0; k < 64; ++k)
        acc = fmaf(xr[k], W[k * 64 + f], acc);

    h[(size_t)i * 64 + f] = acc;

    float ps = acc * a[f];
    float pt = acc * a[64 + f];
    if (f < DINT) {
        float e = ie[(size_t)i * DINT + f];
        ps = fmaf(e, a[128 + f], ps);
        pt = fmaf(e, a[160 + f], pt);
    }
    // full-wave (64-lane) butterfly sum
    #pragma unroll
    for (int m = 1; m < 64; m <<= 1) {
        ps += __shfl_xor(ps, m, 64);
        pt += __shfl_xor(pt, m, 64);
    }
    if (f == 0) { s[i] = ps; t[i] = pt; }
}

// ---------------------------------------------------------------------------
// K2: s_max = max_i s[i]  (single block; trivial cost)
// ---------------------------------------------------------------------------
__global__ __launch_bounds__(256) void k_smax(
    const float* __restrict__ s, float* __restrict__ smax)
{
    float m = -1e30f;
    for (int i = threadIdx.x; i < N_NODES; i += 256)
        m = fmaxf(m, s[i]);
    #pragma unroll
    for (int off = 32; off; off >>= 1)
        m = fmaxf(m, __shfl_down(m, off, 64));
    __shared__ float red[4];
    if ((threadIdx.x & 63) == 0) red[threadIdx.x >> 6] = m;
    __syncthreads();
    if (threadIdx.x == 0)
        smax[0] = fmaxf(fmaxf(red[0], red[1]), fmaxf(red[2], red[3]));
}

// ---------------------------------------------------------------------------
// K3: invD[j] = 1 / sum_i exp(lrelu(s_i + t_j) - c_j),  c_j = lrelu(smax + t_j)
// One block per column j; 256 threads each sum 32 terms, then reduce.
// ---------------------------------------------------------------------------
__global__ __launch_bounds__(256) void k_pass_a(
    const float* __restrict__ s, const float* __restrict__ t,
    const float* __restrict__ smax_p, float* __restrict__ invD)
{
    const int j = blockIdx.x;
    const float tj = t[j];
    const float smax = *smax_p;
    const float zc = smax + tj;
    const float c = fmaxf(zc, ALPHA * zc);   // lrelu(smax + t_j): exact column max

    float acc = 0.f;
    for (int i = threadIdx.x; i < N_NODES; i += 256) {
        float z = s[i] + tj;
        z = fmaxf(z, ALPHA * z);             // leaky_relu, alpha<1 => max(z, a*z)
        acc += __expf(z - c);
    }
    #pragma unroll
    for (int off = 32; off; off >>= 1)
        acc += __shfl_down(acc, off, 64);
    __shared__ float red[4];
    if ((threadIdx.x & 63) == 0) red[threadIdx.x >> 6] = acc;
    __syncthreads();
    if (threadIdx.x == 0)
        invD[j] = 1.0f / (red[0] + red[1] + red[2] + red[3]);
}

// ---------------------------------------------------------------------------
// K4: partial[chunk][i,f] = sum_{j in chunk} attn(i,j) * h[j,f]
// 64(i) x 64(f) output tile per block; j swept in 64-wide tiles.
// Weights computed on the fly into LDS (transposed: wt_s[jj][ii] so the
// matmul reads both operands as 16B-aligned float4; stride 68 keeps float4
// alignment and <=2-way bank aliasing, which is free on gfx950).
// ---------------------------------------------------------------------------
__global__ __launch_bounds__(256) void k_pass_b(
    const float* __restrict__ h, const float* __restrict__ s,
    const float* __restrict__ t, const float* __restrict__ invD,
    const float* __restrict__ smax_p, float* __restrict__ part,
    int tilesPerChunk)
{
    __shared__ __align__(16) float h_s[64][68];   // h_s[jj][f]
    __shared__ __align__(16) float wt_s[64][68];  // wt_s[jj][ii]  (transposed weights)
    __shared__ float s_s[64];
    __shared__ float t_s[64];
    __shared__ float d_s[64];

    const int bi    = blockIdx.x;        // i-tile (0..127)
    const int chunk = blockIdx.y;        // j-chunk
    const int tid   = threadIdx.x;       // 0..255
    const int ty = tid >> 4, tx = tid & 15;
    const int row0 = ty * 4, col0 = tx * 4;
    const float smax = *smax_p;

    if (tid < 64) s_s[tid] = s[bi * 64 + tid];

    float acc[4][4] = {};

    const int jt0 = chunk * tilesPerChunk;
    for (int jt = jt0; jt < jt0 + tilesPerChunk; ++jt) {
        const int j0 = jt * 64;

        if (tid < 64) { t_s[tid] = t[j0 + tid]; d_s[tid] = invD[j0 + tid]; }
        #pragma unroll
        for (int l = 0; l < 4; ++l) {            // stage h tile, float4-coalesced
            int idx = tid + l * 256;             // 0..1023
            int jj = idx >> 4, f4 = (idx & 15) * 4;
            *reinterpret_cast<float4*>(&h_s[jj][f4]) =
                *reinterpret_cast<const float4*>(&h[(size_t)(j0 + jj) * 64 + f4]);
        }
        __syncthreads();

        // weights: wt_s[jj][ii] = exp(lrelu(s_i + t_j) - c_j) * invD_j
        #pragma unroll
        for (int l = 0; l < 16; ++l) {
            int idx = tid + l * 256;             // 0..4095
            int jj = idx >> 6, ii = idx & 63;    // jj wave-uniform, ii = lane
            float tj = t_s[jj];
            float z = s_s[ii] + tj;
            z = fmaxf(z, ALPHA * z);
            float zc = smax + tj;
            float c = fmaxf(zc, ALPHA * zc);     // identical formula to k_pass_a
            wt_s[jj][ii] = __expf(z - c) * d_s[jj];
        }
        __syncthreads();

        #pragma unroll 8
        for (int jj = 0; jj < 64; ++jj) {
            float4 b  = *reinterpret_cast<const float4*>(&h_s[jj][col0]);
            float4 av = *reinterpret_cast<const float4*>(&wt_s[jj][row0]);
            acc[0][0] = fmaf(av.x, b.x, acc[0][0]); acc[0][1] = fmaf(av.x, b.y, acc[0][1]);
            acc[0][2] = fmaf(av.x, b.z, acc[0][2]); acc[0][3] = fmaf(av.x, b.w, acc[0][3]);
            acc[1][0] = fmaf(av.y, b.x, acc[1][0]); acc[1][1] = fmaf(av.y, b.y, acc[1][1]);
            acc[1][2] = fmaf(av.y, b.z, acc[1][2]); acc[1][3] = fmaf(av.y, b.w, acc[1][3]);
            acc[2][0] = fmaf(av.z, b.x, acc[2][0]); acc[2][1] = fmaf(av.z, b.y, acc[2][1]);
            acc[2][2] = fmaf(av.z, b.z, acc[2][2]); acc[2][3] = fmaf(av.z, b.w, acc[2][3]);
            acc[3][0] = fmaf(av.w, b.x, acc[3][0]); acc[3][1] = fmaf(av.w, b.y, acc[3][1]);
            acc[3][2] = fmaf(av.w, b.z, acc[3][2]); acc[3][3] = fmaf(av.w, b.w, acc[3][3]);
        }
        __syncthreads();
    }

    float* dst = part + (size_t)chunk * (N_NODES * F_OUT);
    #pragma unroll
    for (int r = 0; r < 4; ++r) {
        float4 v = make_float4(acc[r][0], acc[r][1], acc[r][2], acc[r][3]);
        *reinterpret_cast<float4*>(&dst[(size_t)(bi * 64 + row0 + r) * 64 + col0]) = v;
    }
}

// ---------------------------------------------------------------------------
// K5: out = elu(sum over chunks of partial)
// ---------------------------------------------------------------------------
__global__ __launch_bounds__(256) void k_combine(
    const float* __restrict__ part, float* __restrict__ out, int nchunk)
{
    const int gid = blockIdx.x * 256 + threadIdx.x;   // 0..131071 (float4 units)
    const float4* p = reinterpret_cast<const float4*>(part);
    float4 v = p[gid];
    for (int c = 1; c < nchunk; ++c) {
        float4 u = p[(size_t)c * (N_NODES * F_OUT / 4) + gid];
        v.x += u.x; v.y += u.y; v.z += u.z; v.w += u.w;
    }
    float4 o;
    o.x = v.x > 0.f ? v.x : expm1f(v.x);
    o.y = v.y > 0.f ? v.y : expm1f(v.y);
    o.z = v.z > 0.f ? v.z : expm1f(v.z);
    o.w = v.w > 0.f ? v.w : expm1f(v.w);
    reinterpret_cast<float4*>(out)[gid] = o;
}

// ---------------------------------------------------------------------------
extern "C" void kernel_launch(void* const* d_in, const int* in_sizes, int n_in,
                              void* d_out, int out_size, void* d_ws, size_t ws_size,
                              hipStream_t stream)
{
    // dict order: input, adj (unused by reference!), intent_embeds, W, a
    const float* x  = (const float*)d_in[0];
    const float* ie = (const float*)d_in[2];
    const float* W  = (const float*)d_in[3];
    const float* a  = (const float*)d_in[4];
    float* out = (float*)d_out;

    float* ws   = (float*)d_ws;
    float* h    = ws;                       // 8192*64
    float* s    = h + N_NODES * F_OUT;      // 8192
    float* t    = s + N_NODES;              // 8192
    float* invD = t + N_NODES;              // 8192
    float* smax = invD + N_NODES;           // 1 (+15 pad for alignment)
    float* part = smax + 16;                // nchunk * 8192*64

    // adaptive j-split: prefer 4 chunks (512 blocks = 2/CU) if ws allows
    const size_t base_bytes  = (size_t)(part - ws) * sizeof(float);
    const size_t chunk_bytes = (size_t)N_NODES * F_OUT * sizeof(float);
    int nchunk = 1;
    if      (ws_size >= base_bytes + 4 * chunk_bytes) nchunk = 4;
    else if (ws_size >= base_bytes + 2 * chunk_bytes) nchunk = 2;
    const int tilesPerChunk = (N_NODES / 64) / nchunk;

    k_h_st  <<<N_NODES, 64,  0, stream>>>(x, ie, W, a, h, s, t);
    k_smax  <<<1,       256, 0, stream>>>(s, smax);
    k_pass_a<<<N_NODES, 256, 0, stream>>>(s, t, smax, invD);
    k_pass_b<<<dim3(128, nchunk), 256, 0, stream>>>(h, s, t, invD, smax, part,
                                                    tilesPerChunk);
    k_combine<<<N_NODES * F_OUT / 4 / 256, 256, 0, stream>>>(part, out, nchunk);
}

// Round 2
// 379.677 us; speedup vs baseline: 1.3267x; 1.3267x over previous
//
#include <hip/hip_runtime.h>
#include <cstdint>
#include <cstddef>

#define N_NODES 8192
#define F_OUT   64
#define DINT    32
#define ALPHA   0.2f

// ---------------------------------------------------------------------------
// K1: h = x @ W, fused s,t projections. One wave per row.
// ---------------------------------------------------------------------------
__global__ __launch_bounds__(64) void k_h_st(
    const float* __restrict__ x, const float* __restrict__ ie,
    const float* __restrict__ W, const float* __restrict__ a,
    float* __restrict__ h, float* __restrict__ s, float* __restrict__ t)
{
    const int i = blockIdx.x;
    const int f = threadIdx.x;              // 0..63
    const float* xr = x + (size_t)i * 64;

    float acc = 0.f;
    #pragma unroll 16
    for (int k = 0; k < 64; ++k)
        acc = fmaf(xr[k], W[k * 64 + f], acc);

    h[(size_t)i * 64 + f] = acc;

    float ps = acc * a[f];
    float pt = acc * a[64 + f];
    if (f < DINT) {
        float e = ie[(size_t)i * DINT + f];
        ps = fmaf(e, a[128 + f], ps);
        pt = fmaf(e, a[160 + f], pt);
    }
    #pragma unroll
    for (int m = 1; m < 64; m <<= 1) {
        ps += __shfl_xor(ps, m, 64);
        pt += __shfl_xor(pt, m, 64);
    }
    if (f == 0) { s[i] = ps; t[i] = pt; }
}

// ---------------------------------------------------------------------------
// K2: smax = max_i s[i]
// ---------------------------------------------------------------------------
__global__ __launch_bounds__(256) void k_smax(
    const float* __restrict__ s, float* __restrict__ smax)
{
    float m = -1e30f;
    for (int i = threadIdx.x; i < N_NODES; i += 256)
        m = fmaxf(m, s[i]);
    #pragma unroll
    for (int off = 32; off; off >>= 1)
        m = fmaxf(m, __shfl_down(m, off, 64));
    __shared__ float red[4];
    if ((threadIdx.x & 63) == 0) red[threadIdx.x >> 6] = m;
    __syncthreads();
    if (threadIdx.x == 0)
        smax[0] = fmaxf(fmaxf(red[0], red[1]), fmaxf(red[2], red[3]));
}

// ---------------------------------------------------------------------------
// K3: brute-force rank/count kernel. One wave per output index.
//  which==0 (idx=i): rank_s[i] (tie-break by index), pos[i]=#{j: t_j < -s_i};
//                    also scatters e^{s_i-smax}, e^{a(s_i-smax)} to sorted slot.
//  which==1 (idx=j): rank_t[j] (tie-break by index), q[j]=#{i: s_i < -t_j}.
// Counts packed into one int (c1*16384 + c2) for a single butterfly reduce.
// ---------------------------------------------------------------------------
__global__ __launch_bounds__(256) void k_ranks(
    const float* __restrict__ s, const float* __restrict__ t,
    const float* __restrict__ smax_p,
    int* __restrict__ rank_s, int* __restrict__ pos,
    int* __restrict__ rank_t, int* __restrict__ q,
    float* __restrict__ se1, float* __restrict__ se2)
{
    const int wave = threadIdx.x >> 6, lane = threadIdx.x & 63;
    const int idx = blockIdx.x * 4 + wave;      // 0..8191
    const int which = blockIdx.y;
    int c1 = 0, c2 = 0;
    if (which == 0) {
        const float si = s[idx], nsi = -si;
        for (int k = lane; k < N_NODES; k += 64) {
            float sk = s[k];
            c1 += (sk < si) || (sk == si && k < idx);
            c2 += (t[k] < nsi);
        }
    } else {
        const float tj = t[idx], ntj = -tj;
        for (int k = lane; k < N_NODES; k += 64) {
            float tk = t[k];
            c1 += (tk < tj) || (tk == tj && k < idx);
            c2 += (s[k] < ntj);
        }
    }
    int p = c1 * 16384 + c2;
    #pragma unroll
    for (int m = 1; m < 64; m <<= 1) p += __shfl_xor(p, m, 64);
    if (lane == 0) {
        int r1 = p >> 14, r2 = p & 16383;
        if (which == 0) {
            rank_s[idx] = r1;
            pos[idx] = r2;
            float d = s[idx] - smax_p[0];
            se1[r1] = __expf(d);
            se2[r1] = __expf(ALPHA * d);
        } else {
            rank_t[idx] = r1;
            q[idx] = r2;
        }
    }
}

// ---------------------------------------------------------------------------
// K4: scalar scans (fp64 accumulation), single block.
//  SufP1[k] = sum_{k'>=k} se1[k'], SufP1[8192]=0   (inclusive suffix)
//  PreP2[k] = sum_{k'<k}  se2[k'], PreP2[0]=0      (exclusive prefix)
// ---------------------------------------------------------------------------
__global__ __launch_bounds__(1024) void k_scanP(
    const float* __restrict__ se1, const float* __restrict__ se2,
    float* __restrict__ SufP1, float* __restrict__ PreP2)
{
    __shared__ double sc[1024];
    const int tid = threadIdx.x;
    double loc[8], sum;

    // PreP2 (exclusive prefix of se2)
    sum = 0.0;
    #pragma unroll
    for (int k = 0; k < 8; ++k) { loc[k] = (double)se2[tid * 8 + k]; sum += loc[k]; }
    sc[tid] = sum; __syncthreads();
    for (int off = 1; off < 1024; off <<= 1) {
        double v = (tid >= off) ? sc[tid - off] : 0.0;
        __syncthreads();
        sc[tid] += v;
        __syncthreads();
    }
    {
        double run = sc[tid] - sum;      // exclusive chunk offset
        #pragma unroll
        for (int k = 0; k < 8; ++k) { PreP2[tid * 8 + k] = (float)run; run += loc[k]; }
        if (tid == 1023) PreP2[8192] = (float)run;
    }
    __syncthreads();

    // SufP1 (inclusive suffix of se1)
    sum = 0.0;
    #pragma unroll
    for (int k = 0; k < 8; ++k) { loc[k] = (double)se1[tid * 8 + k]; sum += loc[k]; }
    sc[tid] = sum; __syncthreads();
    for (int off = 1; off < 1024; off <<= 1) {
        double v = (tid >= off) ? sc[tid - off] : 0.0;
        __syncthreads();
        sc[tid] += v;
        __syncthreads();
    }
    {
        double acc = sc[1023] - sc[tid]; // sum of chunks strictly after tid
        #pragma unroll
        for (int k = 7; k >= 0; --k) { acc += loc[k]; SufP1[tid * 8 + k] = (float)acc; }
        if (tid == 1023) SufP1[8192] = 0.f;
    }
}

// ---------------------------------------------------------------------------
// K5: per-column denominators + scatter coefficient rows into t-sorted order.
//  D_j = e^{pe}·SufP1[q_j] + e^{ne}·PreP2[q_j]   (D_j >= 1 always)
//  G1[rank_t[j]][f] = (e^{pe}/D_j)·h[j][f],  G2[...] = (e^{ne}/D_j)·h[j][f]
// ---------------------------------------------------------------------------
__global__ __launch_bounds__(256) void k_coef(
    const float* __restrict__ h, const float* __restrict__ t,
    const float* __restrict__ smax_p,
    const int* __restrict__ rank_t, const int* __restrict__ q,
    const float* __restrict__ SufP1, const float* __restrict__ PreP2,
    float* __restrict__ G1, float* __restrict__ G2)
{
    const int j = blockIdx.x * 4 + (threadIdx.x >> 6);
    const int f = threadIdx.x & 63;
    const float smax = smax_p[0];
    const float zc = smax + t[j];
    const float c = fmaxf(zc, ALPHA * zc);   // lrelu(smax+t_j) = column max
    const float pe = zc - c;                 // <= 0
    const float ne = ALPHA * zc - c;         // <= 0
    const int qj = q[j];
    const float E1 = __expf(pe), E2 = __expf(ne);
    const float D = E1 * SufP1[qj] + E2 * PreP2[qj];
    const float invD = 1.f / D;
    const float hv = h[(size_t)j * 64 + f];
    const int r = rank_t[j];
    G1[(size_t)r * 64 + f] = (E1 * invD) * hv;
    G2[(size_t)r * 64 + f] = (E2 * invD) * hv;
}

// ---------------------------------------------------------------------------
// K6: per-tile column sums of G1/G2 (level 1 of the big scans)
// ---------------------------------------------------------------------------
__global__ __launch_bounds__(256) void k_tilesum(
    const float* __restrict__ G1, const float* __restrict__ G2,
    float* __restrict__ T1, float* __restrict__ T2)
{
    const int tile = blockIdx.x;       // 0..63 (128 rows each)
    const int arr  = blockIdx.y;       // 0/1
    const float* G = arr ? G2 : G1;
    float* T = arr ? T2 : T1;
    const int f = threadIdx.x & 63, seg = threadIdx.x >> 6;
    const int r0 = tile * 128 + seg * 32;
    float acc = 0.f;
    for (int r = 0; r < 32; ++r) acc += G[(size_t)(r0 + r) * 64 + f];
    __shared__ float red[4][64];
    red[seg][f] = acc; __syncthreads();
    if (seg == 0) T[tile * 64 + f] = red[0][f] + red[1][f] + red[2][f] + red[3][f];
}

// ---------------------------------------------------------------------------
// K7: scan tile sums (level 2). O1[t]=sum of tiles after t; O2[t]=tiles before.
// ---------------------------------------------------------------------------
__global__ __launch_bounds__(128) void k_tilescan(
    const float* __restrict__ T1, const float* __restrict__ T2,
    float* __restrict__ O1, float* __restrict__ O2)
{
    const int tid = threadIdx.x;
    if (tid < 64) {
        float acc = 0.f;
        for (int t = 63; t >= 0; --t) { O1[t * 64 + tid] = acc; acc += T1[t * 64 + tid]; }
    } else {
        const int f = tid - 64;
        float acc = 0.f;
        for (int t = 0; t < 64; ++t) { O2[t * 64 + f] = acc; acc += T2[t * 64 + f]; }
    }
}

// ---------------------------------------------------------------------------
// K8: in-place level-3 scan: G1 -> S1 (inclusive suffix), G2 -> S2 (exclusive
// prefix). Batched 8-row loads keep L2 latency off the critical path.
// Row 8192: S1=0, S2=grand total.
// ---------------------------------------------------------------------------
__global__ __launch_bounds__(64) void k_scan2(
    float* __restrict__ G1, float* __restrict__ G2,
    const float* __restrict__ O1, const float* __restrict__ O2)
{
    const int tile = blockIdx.x, arr = blockIdx.y, f = threadIdx.x;
    if (arr == 0) {
        float acc = O1[tile * 64 + f];
        if (tile == 63) G1[(size_t)8192 * 64 + f] = 0.f;
        for (int rb = 15; rb >= 0; --rb) {
            const int r0 = tile * 128 + rb * 8;
            float v[8];
            #pragma unroll
            for (int k = 0; k < 8; ++k) v[k] = G1[(size_t)(r0 + k) * 64 + f];
            #pragma unroll
            for (int k = 7; k >= 0; --k) { acc += v[k]; G1[(size_t)(r0 + k) * 64 + f] = acc; }
        }
    } else {
        float acc = O2[tile * 64 + f];
        for (int rb = 0; rb < 16; ++rb) {
            const int r0 = tile * 128 + rb * 8;
            float v[8];
            #pragma unroll
            for (int k = 0; k < 8; ++k) v[k] = G2[(size_t)(r0 + k) * 64 + f];
            #pragma unroll
            for (int k = 0; k < 8; ++k) { float old = v[k]; G2[(size_t)(r0 + k) * 64 + f] = acc; acc += old; }
        }
        if (tile == 63) G2[(size_t)8192 * 64 + f] = acc;
    }
}

// ---------------------------------------------------------------------------
// K9: out[i,f] = elu( e^{s_i-smax}·S1[pos_i][f] + e^{a(s_i-smax)}·S2[pos_i][f] )
// ---------------------------------------------------------------------------
__global__ __launch_bounds__(256) void k_out(
    const float* __restrict__ s, const float* __restrict__ smax_p,
    const int* __restrict__ pos,
    const float* __restrict__ G1, const float* __restrict__ G2,
    float* __restrict__ out)
{
    const int i = blockIdx.x * 4 + (threadIdx.x >> 6);
    const int f = threadIdx.x & 63;
    const float d = s[i] - smax_p[0];
    const float e1 = __expf(d), e2 = __expf(ALPHA * d);
    const int p = pos[i];
    float v = e1 * G1[(size_t)p * 64 + f] + e2 * G2[(size_t)p * 64 + f];
    out[(size_t)i * 64 + f] = v > 0.f ? v : expm1f(v);
}

// ---------------------------------------------------------------------------
extern "C" void kernel_launch(void* const* d_in, const int* in_sizes, int n_in,
                              void* d_out, int out_size, void* d_ws, size_t ws_size,
                              hipStream_t stream)
{
    // dict order: input, adj (unused by reference), intent_embeds, W, a
    const float* x  = (const float*)d_in[0];
    const float* ie = (const float*)d_in[2];
    const float* W  = (const float*)d_in[3];
    const float* a  = (const float*)d_in[4];
    float* out = (float*)d_out;

    float* p = (float*)d_ws;
    float* h     = p; p += (size_t)N_NODES * F_OUT;     // 524288
    float* s     = p; p += N_NODES;
    float* t     = p; p += N_NODES;
    float* smax  = p; p += 16;
    float* se1   = p; p += N_NODES;
    float* se2   = p; p += N_NODES;
    float* SufP1 = p; p += N_NODES + 16;                // 8193 used
    float* PreP2 = p; p += N_NODES + 16;
    float* T1    = p; p += 64 * 64;
    float* T2    = p; p += 64 * 64;
    float* O1    = p; p += 64 * 64;
    float* O2    = p; p += 64 * 64;
    float* G1    = p; p += (size_t)(N_NODES + 1) * F_OUT + 48;  // 8193 rows
    float* G2    = p; p += (size_t)(N_NODES + 1) * F_OUT + 48;
    int* rank_s  = (int*)p; p += N_NODES;
    int* rank_t  = (int*)p; p += N_NODES;
    int* pos     = (int*)p; p += N_NODES;
    int* q       = (int*)p; p += N_NODES;
    // total ~6.7 MB < ws_size (round-1 confirmed >= ~10.6 MB available)

    k_h_st    <<<N_NODES, 64, 0, stream>>>(x, ie, W, a, h, s, t);
    k_smax    <<<1, 256, 0, stream>>>(s, smax);
    k_ranks   <<<dim3(N_NODES / 4, 2), 256, 0, stream>>>(s, t, smax,
                      rank_s, pos, rank_t, q, se1, se2);
    k_scanP   <<<1, 1024, 0, stream>>>(se1, se2, SufP1, PreP2);
    k_coef    <<<N_NODES / 4, 256, 0, stream>>>(h, t, smax, rank_t, q,
                      SufP1, PreP2, G1, G2);
    k_tilesum <<<dim3(64, 2), 256, 0, stream>>>(G1, G2, T1, T2);
    k_tilescan<<<1, 128, 0, stream>>>(T1, T2, O1, O2);
    k_scan2   <<<dim3(64, 2), 64, 0, stream>>>(G1, G2, O1, O2);
    k_out     <<<N_NODES / 4, 256, 0, stream>>>(s, smax, pos, G1, G2, out);
}